// Round 3
// baseline (342.578 us; speedup 1.0000x reference)
//
#include <hip/hip_runtime.h>
#include <hip/hip_bf16.h>
#include <hip/hip_cooperative_groups.h>

// MLA-absorbed latent attention (round 12).
// r11: 137.3us (-1.7). Model: ~87us harness fills (fixed) + ~30-35us kernels
// + ~15us inter-dispatch gaps. r12: fuse all 4 phases into ONE cooperative
// kernel (512 blocks, 2/CU co-resident, LDS union 52.2KB, grid.sync between
// phases) to eliminate 3 launch/drain boundaries. Phase bodies unchanged from
// the verified r11 kernels; only block->tile mappings changed.

namespace cg = cooperative_groups;

typedef __bf16 bf16_t;
typedef bf16_t bf16x8 __attribute__((ext_vector_type(8)));
typedef float f32x4 __attribute__((ext_vector_type(4)));

__device__ inline bf16x8 cvt8(const float* __restrict__ p) {
  f32x4 a = *(const f32x4*)p, b = *(const f32x4*)(p + 4);
  bf16x8 r;
#pragma unroll
  for (int i = 0; i < 4; ++i) { r[i] = (bf16_t)a[i]; r[4 + i] = (bf16_t)b[i]; }
  return r;
}

__global__ __launch_bounds__(256, 2) void fused_mla(
    const float* __restrict__ x, const float* __restrict__ wq,
    const float* __restrict__ wkd, const float* __restrict__ wvd,
    const float* __restrict__ wku, const float* __restrict__ wvu,
    const float* __restrict__ wo, bf16_t* __restrict__ Xb,
    bf16_t* __restrict__ WqkvT, bf16_t* __restrict__ WcombT,
    bf16_t* __restrict__ QKV, float* __restrict__ out) {
  cg::grid_group grid = cg::this_grid();

  __shared__ __align__(16) union SM {
    char prep[34816];
    struct { bf16_t As[32][72]; bf16_t Bs[128][72]; } g1;
    struct { bf16_t Ks[2][128][36]; bf16_t Vt[2][32][132]; bf16_t Ps[4][16][132]; } at;
    struct { bf16_t As[64][72]; bf16_t Bs[128][72]; } g2;
  } sm;

  const int tid = threadIdx.x;
  const int wave = tid >> 6, lane = tid & 63;
  const int quad = lane >> 4, col = lane & 15;
  const int bi = blockIdx.x;

  // ===================== phase 0: weight prep + x cast =====================
  if (bi < 64) { // wq_eff^T[32h+l][c] = sum_d wku[l][d]*wq[c][128h+d]
    const int h = bi >> 3;
    const int c0 = (bi & 7) * 128 + wave * 32;
    f32x4 acc[2][2];
#pragma unroll
    for (int i = 0; i < 2; ++i)
#pragma unroll
      for (int j = 0; j < 2; ++j) acc[i][j] = (f32x4){0.f, 0.f, 0.f, 0.f};
#pragma unroll
    for (int ks = 0; ks < 4; ++ks) {
      const int ko = ks * 32 + quad * 8;
      bf16x8 a0 = cvt8(wku + col * 128 + ko);
      bf16x8 a1 = cvt8(wku + (16 + col) * 128 + ko);
      bf16x8 b0 = cvt8(wq + (size_t)(c0 + col) * 1024 + h * 128 + ko);
      bf16x8 b1 = cvt8(wq + (size_t)(c0 + 16 + col) * 1024 + h * 128 + ko);
      acc[0][0] = __builtin_amdgcn_mfma_f32_16x16x32_bf16(a0, b0, acc[0][0], 0, 0, 0);
      acc[0][1] = __builtin_amdgcn_mfma_f32_16x16x32_bf16(a0, b1, acc[0][1], 0, 0, 0);
      acc[1][0] = __builtin_amdgcn_mfma_f32_16x16x32_bf16(a1, b0, acc[1][0], 0, 0, 0);
      acc[1][1] = __builtin_amdgcn_mfma_f32_16x16x32_bf16(a1, b1, acc[1][1], 0, 0, 0);
    }
#pragma unroll
    for (int ms = 0; ms < 2; ++ms)
#pragma unroll
      for (int ns = 0; ns < 2; ++ns)
#pragma unroll
        for (int v = 0; v < 4; ++v)
          WqkvT[(size_t)(h * 32 + ms * 16 + quad * 4 + v) * 1024 + c0 + ns * 16 + col] =
              (bf16_t)acc[ms][ns][v];
  } else if (bi < 128) { // WcombT[m][32h+l] = sum_d wvu[l][d]*wo[128h+d][m]
    const int b2 = bi - 64;
    const int h = b2 >> 3, m0 = (b2 & 7) * 128;
    bf16_t(*B_lds)[136] = (bf16_t(*)[136])sm.prep; // [m][d]
    {
      const int d = tid >> 1, mh = (tid & 1) * 64;
      const float* wp = wo + (size_t)(h * 128 + d) * 1024 + m0 + mh;
#pragma unroll
      for (int i = 0; i < 16; ++i) {
        f32x4 w4 = *(const f32x4*)(wp + i * 4);
#pragma unroll
        for (int t = 0; t < 4; ++t) B_lds[mh + i * 4 + t][d] = (bf16_t)w4[t];
      }
    }
    __syncthreads();
    f32x4 acc[2][2];
#pragma unroll
    for (int i = 0; i < 2; ++i)
#pragma unroll
      for (int j = 0; j < 2; ++j) acc[i][j] = (f32x4){0.f, 0.f, 0.f, 0.f};
#pragma unroll
    for (int ks = 0; ks < 4; ++ks) {
      const int ko = ks * 32 + quad * 8;
      bf16x8 a0 = cvt8(wvu + col * 128 + ko);
      bf16x8 a1 = cvt8(wvu + (16 + col) * 128 + ko);
      bf16x8 b0 = *(const bf16x8*)&B_lds[wave * 32 + col][ko];
      bf16x8 b1 = *(const bf16x8*)&B_lds[wave * 32 + 16 + col][ko];
      acc[0][0] = __builtin_amdgcn_mfma_f32_16x16x32_bf16(a0, b0, acc[0][0], 0, 0, 0);
      acc[0][1] = __builtin_amdgcn_mfma_f32_16x16x32_bf16(a0, b1, acc[0][1], 0, 0, 0);
      acc[1][0] = __builtin_amdgcn_mfma_f32_16x16x32_bf16(a1, b0, acc[1][0], 0, 0, 0);
      acc[1][1] = __builtin_amdgcn_mfma_f32_16x16x32_bf16(a1, b1, acc[1][1], 0, 0, 0);
    }
#pragma unroll
    for (int ms = 0; ms < 2; ++ms)
#pragma unroll
      for (int ns = 0; ns < 2; ++ns)
#pragma unroll
        for (int v = 0; v < 4; ++v)
          WcombT[(size_t)(m0 + wave * 32 + ns * 16 + col) * 256 +
                 h * 32 + ms * 16 + quad * 4 + v] = (bf16_t)acc[ms][ns][v];
  } else if (bi < 160) { // wk_down/wv_down transpose into WqkvT rows 256..383
    const int b3 = bi - 128;
    const int mat = b3 >> 4, c0 = (b3 & 15) * 64;
    const float* in = mat ? wvd : wkd;
    bf16_t(*tT)[72] = (bf16_t(*)[72])sm.prep;
    {
      const int cc = tid >> 2, jq = (tid & 3) * 16;
      const float* ip = in + (size_t)(c0 + cc) * 64 + jq;
#pragma unroll
      for (int q = 0; q < 4; ++q) {
        f32x4 v4 = *(const f32x4*)(ip + q * 4);
#pragma unroll
        for (int t = 0; t < 4; ++t) tT[jq + q * 4 + t][cc] = (bf16_t)v4[t];
      }
    }
    __syncthreads();
    {
      const int j = tid >> 2, cq = (tid & 3) * 16;
      bf16_t* op = WqkvT + (size_t)(256 + mat * 64 + j) * 1024 + c0 + cq;
      *(bf16x8*)op = *(const bf16x8*)&tT[j][cq];
      *(bf16x8*)(op + 8) = *(const bf16x8*)&tT[j][cq + 8];
    }
  } else { // bi in [160,512): x f32 -> bf16 cast, grid-stride over 2048-chunks
#pragma unroll
    for (int it = 0; it < 6; ++it) {
      const size_t off = ((size_t)(bi - 160) + (size_t)it * 352) * 2048 + (size_t)tid * 8;
      if (off < (size_t)4096 * 1024) *(bf16x8*)(Xb + off) = cvt8(x + off);
    }
  }
  grid.sync();

  // ===================== phase 1: QKV GEMM (384 units) =====================
  // C_bf16[4096][384] = Xb[4096][1024] @ WqkvT[384][1024]^T, BM=32 BN=128 BK=64
  if (bi < 384) {
    auto& As = sm.g1.As;
    auto& Bs = sm.g1.Bs;
    const int wm = (wave >> 1) * 16, wn = (wave & 1) * 64;
    const int n0 = (bi % 3) * 128, m0 = (bi / 3) * 32;

    f32x4 acc[4];
#pragma unroll
    for (int j = 0; j < 4; ++j) acc[j] = (f32x4){0.f, 0.f, 0.f, 0.f};

    const int ar = tid >> 3, ac = (tid & 7) * 8;
    const int br = tid >> 1, bc = (tid & 1) * 32;
    const bf16_t* aP = Xb + (size_t)(m0 + ar) * 1024 + ac;
    const bf16_t* bP = WqkvT + (size_t)(n0 + br) * 1024 + bc;

    bf16x8 aR0 = *(const bf16x8*)aP;
    bf16x8 bR0 = *(const bf16x8*)bP, bR1 = *(const bf16x8*)(bP + 8);
    bf16x8 bR2 = *(const bf16x8*)(bP + 16), bR3 = *(const bf16x8*)(bP + 24);

    for (int kt = 0; kt < 16; ++kt) {
      *(bf16x8*)&As[ar][ac] = aR0;
      *(bf16x8*)&Bs[br][bc] = bR0; *(bf16x8*)&Bs[br][bc + 8] = bR1;
      *(bf16x8*)&Bs[br][bc + 16] = bR2; *(bf16x8*)&Bs[br][bc + 24] = bR3;
      __syncthreads();
      if (kt < 15) {
        const int k0 = (kt + 1) * 64;
        aR0 = *(const bf16x8*)(aP + k0);
        bR0 = *(const bf16x8*)(bP + k0); bR1 = *(const bf16x8*)(bP + k0 + 8);
        bR2 = *(const bf16x8*)(bP + k0 + 16); bR3 = *(const bf16x8*)(bP + k0 + 24);
      }
#pragma unroll
      for (int ks = 0; ks < 2; ++ks) {
        bf16x8 af = *(const bf16x8*)&As[wm + col][ks * 32 + quad * 8];
        bf16x8 bfr[4];
#pragma unroll
        for (int j = 0; j < 4; ++j) bfr[j] = *(const bf16x8*)&Bs[wn + j * 16 + col][ks * 32 + quad * 8];
#pragma unroll
        for (int j = 0; j < 4; ++j)
          acc[j] = __builtin_amdgcn_mfma_f32_16x16x32_bf16(af, bfr[j], acc[j], 0, 0, 0);
      }
      __syncthreads();
    }

#pragma unroll
    for (int j = 0; j < 4; ++j) {
      const int cg_ = n0 + wn + j * 16 + col;
#pragma unroll
      for (int v = 0; v < 4; ++v)
        QKV[(size_t)(m0 + wm + quad * 4 + v) * 384 + cg_] = (bf16_t)acc[j][v];
    }
  }
  grid.sync();

  // ===================== phase 2: latent flash attention (512 units) =====================
  {
    auto& Ks = sm.at.Ks;
    auto& Vt = sm.at.Vt;
    auto& Ps = sm.at.Ps;
    const int half = bi >> 8, rest = bi & 255;
    const int qt = half ? 127 - (rest >> 1) : (rest >> 1);
    const int hkv = rest & 1, b = half;

    const int qb = qt * 16;
    const size_t rowbase = (size_t)b * 2048;
    const int qcol0 = (hkv * 4 + wave) * 32;

    bf16x8 a_q = *(const bf16x8*)(QKV + (rowbase + qb + col) * 384 + qcol0 + quad * 8);

    f32x4 o0 = (f32x4){0.f, 0.f, 0.f, 0.f};
    f32x4 o1 = (f32x4){0.f, 0.f, 0.f, 0.f};
    float lsum[4] = {0.f, 0.f, 0.f, 0.f};

    const int nkt = (qb >> 7) + 1;
    const float scale = 0.08838834764831843f; // 1/sqrt(128)

    const int kr = tid >> 1, dc = (tid & 1) * 16;
    const bf16_t* kvBase = QKV + (rowbase + kr) * 384 + 256 + hkv * 32 + dc;

    {
      bf16x8 kA = *(const bf16x8*)kvBase, kB = *(const bf16x8*)(kvBase + 8);
      bf16x8 vA = *(const bf16x8*)(kvBase + 64), vB = *(const bf16x8*)(kvBase + 72);
      *(bf16x8*)&Ks[0][kr][dc] = kA;
      *(bf16x8*)&Ks[0][kr][dc + 8] = kB;
#pragma unroll
      for (int t = 0; t < 8; ++t) { Vt[0][dc + t][kr] = vA[t]; Vt[0][dc + 8 + t][kr] = vB[t]; }
    }
    __syncthreads();

    for (int kt = 0; kt < nkt; ++kt) {
      const int cur = kt & 1;
      const int kb = kt * 128;
      const bool more = (kt + 1 < nkt);

      bf16x8 kA, kB, vA, vB;
      if (more) {
        const bf16_t* np = kvBase + (size_t)(kt + 1) * 128 * 384;
        kA = *(const bf16x8*)np; kB = *(const bf16x8*)(np + 8);
        vA = *(const bf16x8*)(np + 64); vB = *(const bf16x8*)(np + 72);
      }

      f32x4 s[8];
#pragma unroll
      for (int k8 = 0; k8 < 8; ++k8) {
        bf16x8 bk = *(const bf16x8*)&Ks[cur][k8 * 16 + col][quad * 8];
        s[k8] = __builtin_amdgcn_mfma_f32_16x16x32_bf16(a_q, bk, (f32x4){0.f, 0.f, 0.f, 0.f}, 0, 0, 0);
      }

      const bool full = (kb + 128 <= qb);
#pragma unroll
      for (int v = 0; v < 4; ++v) {
        const int qr = quad * 4 + v;
        const int qg = qb + qr;
#pragma unroll
        for (int k8 = 0; k8 < 8; ++k8) {
          float xx = s[k8][v] * scale;
          if (!full && (kb + k8 * 16 + col > qg)) xx = -1e30f;
          const float p = __expf(xx);
          lsum[v] += p;
          Ps[wave][qr][k8 * 16 + col] = (bf16_t)p;
        }
      }
      __asm__ __volatile__("" ::: "memory"); // Ps: same-wave LDS, order only

#pragma unroll
      for (int kc = 0; kc < 4; ++kc) {
        bf16x8 a_p = *(const bf16x8*)&Ps[wave][col][kc * 32 + quad * 8];
        bf16x8 bv0 = *(const bf16x8*)&Vt[cur][col][kc * 32 + quad * 8];
        bf16x8 bv1 = *(const bf16x8*)&Vt[cur][16 + col][kc * 32 + quad * 8];
        o0 = __builtin_amdgcn_mfma_f32_16x16x32_bf16(a_p, bv0, o0, 0, 0, 0);
        o1 = __builtin_amdgcn_mfma_f32_16x16x32_bf16(a_p, bv1, o1, 0, 0, 0);
      }

      if (more) {
        *(bf16x8*)&Ks[cur ^ 1][kr][dc] = kA;
        *(bf16x8*)&Ks[cur ^ 1][kr][dc + 8] = kB;
#pragma unroll
        for (int t = 0; t < 8; ++t) { Vt[cur ^ 1][dc + t][kr] = vA[t]; Vt[cur ^ 1][dc + 8 + t][kr] = vB[t]; }
      }
      __syncthreads();
    }

#pragma unroll
    for (int v = 0; v < 4; ++v) {
      float l = lsum[v];
#pragma unroll
      for (int off = 8; off; off >>= 1) l += __shfl_xor(l, off, 64);
      const float inv = 1.f / l;
      const size_t r = (rowbase + qb + quad * 4 + v) * 384 + qcol0;
      QKV[r + col] = (bf16_t)(o0[v] * inv);
      QKV[r + 16 + col] = (bf16_t)(o1[v] * inv);
    }
  }
  grid.sync();

  // ===================== phase 3: out GEMM (512 units) =====================
  // C_f32[4096][1024] = QKV[4096][lda=384,K=256] @ WcombT[1024][256]^T, BM=64 BN=128
  {
    auto& As = sm.g2.As;
    auto& Bs = sm.g2.Bs;
    const int wm = (wave >> 1) * 32, wn = (wave & 1) * 64;
    const int m0 = (bi >> 3) * 64, n0 = (bi & 7) * 128;

    f32x4 acc[2][4];
#pragma unroll
    for (int i = 0; i < 2; ++i)
#pragma unroll
      for (int j = 0; j < 4; ++j) acc[i][j] = (f32x4){0.f, 0.f, 0.f, 0.f};

    const int ar = tid >> 2, ac = (tid & 3) * 16;
    const int br = tid >> 1, bc = (tid & 1) * 32;
    const bf16_t* aP = QKV + (size_t)(m0 + ar) * 384 + ac;
    const bf16_t* bP = WcombT + (size_t)(n0 + br) * 256 + bc;

    bf16x8 aR0 = *(const bf16x8*)aP, aR1 = *(const bf16x8*)(aP + 8);
    bf16x8 bR0 = *(const bf16x8*)bP, bR1 = *(const bf16x8*)(bP + 8);
    bf16x8 bR2 = *(const bf16x8*)(bP + 16), bR3 = *(const bf16x8*)(bP + 24);

    for (int kt = 0; kt < 4; ++kt) {
      *(bf16x8*)&As[ar][ac] = aR0; *(bf16x8*)&As[ar][ac + 8] = aR1;
      *(bf16x8*)&Bs[br][bc] = bR0; *(bf16x8*)&Bs[br][bc + 8] = bR1;
      *(bf16x8*)&Bs[br][bc + 16] = bR2; *(bf16x8*)&Bs[br][bc + 24] = bR3;
      __syncthreads();
      if (kt < 3) {
        const int k0 = (kt + 1) * 64;
        aR0 = *(const bf16x8*)(aP + k0); aR1 = *(const bf16x8*)(aP + k0 + 8);
        bR0 = *(const bf16x8*)(bP + k0); bR1 = *(const bf16x8*)(bP + k0 + 8);
        bR2 = *(const bf16x8*)(bP + k0 + 16); bR3 = *(const bf16x8*)(bP + k0 + 24);
      }
#pragma unroll
      for (int ks = 0; ks < 2; ++ks) {
        bf16x8 af[2], bfr[4];
#pragma unroll
        for (int i = 0; i < 2; ++i) af[i] = *(const bf16x8*)&As[wm + i * 16 + col][ks * 32 + quad * 8];
#pragma unroll
        for (int j = 0; j < 4; ++j) bfr[j] = *(const bf16x8*)&Bs[wn + j * 16 + col][ks * 32 + quad * 8];
#pragma unroll
        for (int i = 0; i < 2; ++i)
#pragma unroll
          for (int j = 0; j < 4; ++j)
            acc[i][j] = __builtin_amdgcn_mfma_f32_16x16x32_bf16(af[i], bfr[j], acc[i][j], 0, 0, 0);
      }
      __syncthreads();
    }

#pragma unroll
    for (int i = 0; i < 2; ++i) {
      const int rg = m0 + wm + i * 16 + quad * 4;
#pragma unroll
      for (int j = 0; j < 4; ++j) {
        const int cg_ = n0 + wn + j * 16 + col;
#pragma unroll
        for (int v = 0; v < 4; ++v)
          out[(size_t)(rg + v) * 1024 + cg_] = acc[i][j][v];
      }
    }
  }
}

// ---------------------------------------------------------------------------
extern "C" void kernel_launch(void* const* d_in, const int* in_sizes, int n_in,
                              void* d_out, int out_size, void* d_ws, size_t ws_size,
                              hipStream_t stream) {
  (void)in_sizes; (void)n_in; (void)out_size; (void)ws_size;
  const float* x   = (const float*)d_in[0];
  const float* wq  = (const float*)d_in[1];
  const float* wkd = (const float*)d_in[2];
  const float* wvd = (const float*)d_in[3];
  const float* wku = (const float*)d_in[4];
  const float* wvu = (const float*)d_in[5];
  const float* wo  = (const float*)d_in[6];
  float* out = (float*)d_out;

  // Workspace: ~12.8 MB
  bf16_t* WqkvT  = (bf16_t*)d_ws;                 // [384][1024]
  bf16_t* WcombT = WqkvT + (size_t)384 * 1024;    // [1024][256]
  bf16_t* QKV    = WcombT + (size_t)1024 * 256;   // [4096][384]
  bf16_t* Xb     = QKV + (size_t)4096 * 384;      // [4096][1024]

  void* args[] = {(void*)&x, (void*)&wq, (void*)&wkd, (void*)&wvd,
                  (void*)&wku, (void*)&wvu, (void*)&wo, (void*)&Xb,
                  (void*)&WqkvT, (void*)&WcombT, (void*)&QKV, (void*)&out};
  hipLaunchCooperativeKernel((const void*)fused_mla, dim3(512), dim3(256),
                             args, 0, stream);
}

// Round 4
// 138.638 us; speedup vs baseline: 2.4710x; 2.4710x over previous
//
#include <hip/hip_runtime.h>
#include <hip/hip_bf16.h>

// MLA-absorbed latent attention (round 13).
// r12 post-mortem: cooperative fusion catastrophic (253us kernel; grid.sync
// ~70us each due to cross-XCD coherence flush). REVERTED to r11 structure
// (137.3us verified). r13 delta: XCD-locality block mapping in both GEMMs —
// 1D grids with m0=bi%nrow, n0=bi/nrow so column-tiles sharing an A-row-slice
// land on the SAME XCD (stride 128/64 ≡ 0 mod 8) -> A fetched once per XCD
// instead of 3x/8x. Everything else byte-identical to r11.

typedef __bf16 bf16_t;
typedef bf16_t bf16x8 __attribute__((ext_vector_type(8)));
typedef float f32x4 __attribute__((ext_vector_type(4)));

__device__ inline bf16x8 cvt8(const float* __restrict__ p) {
  f32x4 a = *(const f32x4*)p, b = *(const f32x4*)(p + 4);
  bf16x8 r;
#pragma unroll
  for (int i = 0; i < 4; ++i) { r[i] = (bf16_t)a[i]; r[4 + i] = (bf16_t)b[i]; }
  return r;
}

// ---- one-shot weight prep, all-MFMA, emits bf16 transposed weights + x cast ----
__global__ __launch_bounds__(256) void prep_mfma(
    const float* __restrict__ x, const float* __restrict__ wq,
    const float* __restrict__ wkd, const float* __restrict__ wvd,
    const float* __restrict__ wku, const float* __restrict__ wvu,
    const float* __restrict__ wo, bf16_t* __restrict__ Xb,
    bf16_t* __restrict__ WqkvT, bf16_t* __restrict__ WcombT) {
  __shared__ __align__(16) char smem[34816];
  const int tid = threadIdx.x;
  const int wave = tid >> 6, lane = tid & 63;
  const int quad = lane >> 4, col = lane & 15;
  const int bi = blockIdx.x;

  if (bi < 64) { // wq_eff^T[32h+l][c] = sum_d wku[l][d]*wq[c][128h+d]
    const int h = bi >> 3;
    const int c0 = (bi & 7) * 128 + wave * 32;
    f32x4 acc[2][2];
#pragma unroll
    for (int i = 0; i < 2; ++i)
#pragma unroll
      for (int j = 0; j < 2; ++j) acc[i][j] = (f32x4){0.f, 0.f, 0.f, 0.f};
#pragma unroll
    for (int ks = 0; ks < 4; ++ks) {
      const int ko = ks * 32 + quad * 8;
      bf16x8 a0 = cvt8(wku + col * 128 + ko);
      bf16x8 a1 = cvt8(wku + (16 + col) * 128 + ko);
      bf16x8 b0 = cvt8(wq + (size_t)(c0 + col) * 1024 + h * 128 + ko);
      bf16x8 b1 = cvt8(wq + (size_t)(c0 + 16 + col) * 1024 + h * 128 + ko);
      acc[0][0] = __builtin_amdgcn_mfma_f32_16x16x32_bf16(a0, b0, acc[0][0], 0, 0, 0);
      acc[0][1] = __builtin_amdgcn_mfma_f32_16x16x32_bf16(a0, b1, acc[0][1], 0, 0, 0);
      acc[1][0] = __builtin_amdgcn_mfma_f32_16x16x32_bf16(a1, b0, acc[1][0], 0, 0, 0);
      acc[1][1] = __builtin_amdgcn_mfma_f32_16x16x32_bf16(a1, b1, acc[1][1], 0, 0, 0);
    }
#pragma unroll
    for (int ms = 0; ms < 2; ++ms)
#pragma unroll
      for (int ns = 0; ns < 2; ++ns)
#pragma unroll
        for (int v = 0; v < 4; ++v)
          WqkvT[(size_t)(h * 32 + ms * 16 + quad * 4 + v) * 1024 + c0 + ns * 16 + col] =
              (bf16_t)acc[ms][ns][v];
  } else if (bi < 128) { // WcombT[m][32h+l] = sum_d wvu[l][d]*wo[128h+d][m]
    const int b2 = bi - 64;
    const int h = b2 >> 3, m0 = (b2 & 7) * 128;
    bf16_t(*B_lds)[136] = (bf16_t(*)[136])smem; // [m][d]
    {
      const int d = tid >> 1, mh = (tid & 1) * 64;
      const float* wp = wo + (size_t)(h * 128 + d) * 1024 + m0 + mh;
#pragma unroll
      for (int i = 0; i < 16; ++i) {
        f32x4 w4 = *(const f32x4*)(wp + i * 4);
#pragma unroll
        for (int t = 0; t < 4; ++t) B_lds[mh + i * 4 + t][d] = (bf16_t)w4[t];
      }
    }
    __syncthreads();
    f32x4 acc[2][2];
#pragma unroll
    for (int i = 0; i < 2; ++i)
#pragma unroll
      for (int j = 0; j < 2; ++j) acc[i][j] = (f32x4){0.f, 0.f, 0.f, 0.f};
#pragma unroll
    for (int ks = 0; ks < 4; ++ks) {
      const int ko = ks * 32 + quad * 8;
      bf16x8 a0 = cvt8(wvu + col * 128 + ko);
      bf16x8 a1 = cvt8(wvu + (16 + col) * 128 + ko);
      bf16x8 b0 = *(const bf16x8*)&B_lds[wave * 32 + col][ko];
      bf16x8 b1 = *(const bf16x8*)&B_lds[wave * 32 + 16 + col][ko];
      acc[0][0] = __builtin_amdgcn_mfma_f32_16x16x32_bf16(a0, b0, acc[0][0], 0, 0, 0);
      acc[0][1] = __builtin_amdgcn_mfma_f32_16x16x32_bf16(a0, b1, acc[0][1], 0, 0, 0);
      acc[1][0] = __builtin_amdgcn_mfma_f32_16x16x32_bf16(a1, b0, acc[1][0], 0, 0, 0);
      acc[1][1] = __builtin_amdgcn_mfma_f32_16x16x32_bf16(a1, b1, acc[1][1], 0, 0, 0);
    }
#pragma unroll
    for (int ms = 0; ms < 2; ++ms)
#pragma unroll
      for (int ns = 0; ns < 2; ++ns)
#pragma unroll
        for (int v = 0; v < 4; ++v)
          WcombT[(size_t)(m0 + wave * 32 + ns * 16 + col) * 256 +
                 h * 32 + ms * 16 + quad * 4 + v] = (bf16_t)acc[ms][ns][v];
  } else if (bi < 160) { // wk_down/wv_down transpose into WqkvT rows 256..383
    const int b3 = bi - 128;
    const int mat = b3 >> 4, c0 = (b3 & 15) * 64;
    const float* in = mat ? wvd : wkd;
    bf16_t(*tT)[72] = (bf16_t(*)[72])smem;
    {
      const int cc = tid >> 2, jq = (tid & 3) * 16;
      const float* ip = in + (size_t)(c0 + cc) * 64 + jq;
#pragma unroll
      for (int q = 0; q < 4; ++q) {
        f32x4 v4 = *(const f32x4*)(ip + q * 4);
#pragma unroll
        for (int t = 0; t < 4; ++t) tT[jq + q * 4 + t][cc] = (bf16_t)v4[t];
      }
    }
    __syncthreads();
    {
      const int j = tid >> 2, cq = (tid & 3) * 16;
      bf16_t* op = WqkvT + (size_t)(256 + mat * 64 + j) * 1024 + c0 + cq;
      *(bf16x8*)op = *(const bf16x8*)&tT[j][cq];
      *(bf16x8*)(op + 8) = *(const bf16x8*)&tT[j][cq + 8];
    }
  } else { // bi in [160,288): x f32 -> bf16 cast, 32768 elems/block
    const size_t base = (size_t)(bi - 160) * 32768;
    const float* ip = x + base;
    bf16_t* op = Xb + base;
#pragma unroll
    for (int it = 0; it < 16; ++it) {
      const int o = it * 2048 + tid * 8;
      *(bf16x8*)(op + o) = cvt8(ip + o);
    }
  }
}

// ---- QKV GEMM: C_bf16[4096][384] = A_bf16[4096][1024] @ WqkvT_bf16[384][1024]^T ----
// BM=32 BN=128 BK=64, 1D grid 384. XCD-locality: m0=bi%128, n0=bi/128 so the
// 3 col-tiles of a row-slice (bi, bi+128, bi+256) share an XCD (128%8==0).
__global__ __launch_bounds__(256) void gemm_qkv(
    const bf16_t* __restrict__ A, const bf16_t* __restrict__ Bt,
    bf16_t* __restrict__ C) {
  __shared__ bf16_t As[32][72];
  __shared__ bf16_t Bs[128][72];
  const int tid = threadIdx.x;
  const int wave = tid >> 6, lane = tid & 63;
  const int quad = lane >> 4, col = lane & 15;
  const int wm = (wave >> 1) * 16, wn = (wave & 1) * 64;
  const int bi = blockIdx.x;
  const int m0 = (bi & 127) * 32, n0 = (bi >> 7) * 128;

  f32x4 acc[4];
#pragma unroll
  for (int j = 0; j < 4; ++j) acc[j] = (f32x4){0.f, 0.f, 0.f, 0.f};

  const int ar = tid >> 3, ac = (tid & 7) * 8;   // A: 32 rows x 64k, 8 bf16/thread
  const int br = tid >> 1, bc = (tid & 1) * 32;  // B: 128 rows x 64k
  const bf16_t* aP = A + (size_t)(m0 + ar) * 1024 + ac;
  const bf16_t* bP = Bt + (size_t)(n0 + br) * 1024 + bc;

  bf16x8 aR0 = *(const bf16x8*)aP;
  bf16x8 bR0 = *(const bf16x8*)bP, bR1 = *(const bf16x8*)(bP + 8);
  bf16x8 bR2 = *(const bf16x8*)(bP + 16), bR3 = *(const bf16x8*)(bP + 24);

  for (int kt = 0; kt < 16; ++kt) {
    *(bf16x8*)&As[ar][ac] = aR0;
    *(bf16x8*)&Bs[br][bc] = bR0; *(bf16x8*)&Bs[br][bc + 8] = bR1;
    *(bf16x8*)&Bs[br][bc + 16] = bR2; *(bf16x8*)&Bs[br][bc + 24] = bR3;
    __syncthreads();
    if (kt < 15) {
      const int k0 = (kt + 1) * 64;
      aR0 = *(const bf16x8*)(aP + k0);
      bR0 = *(const bf16x8*)(bP + k0); bR1 = *(const bf16x8*)(bP + k0 + 8);
      bR2 = *(const bf16x8*)(bP + k0 + 16); bR3 = *(const bf16x8*)(bP + k0 + 24);
    }
#pragma unroll
    for (int ks = 0; ks < 2; ++ks) {
      bf16x8 af = *(const bf16x8*)&As[wm + col][ks * 32 + quad * 8];
      bf16x8 bfr[4];
#pragma unroll
      for (int j = 0; j < 4; ++j) bfr[j] = *(const bf16x8*)&Bs[wn + j * 16 + col][ks * 32 + quad * 8];
#pragma unroll
      for (int j = 0; j < 4; ++j)
        acc[j] = __builtin_amdgcn_mfma_f32_16x16x32_bf16(af, bfr[j], acc[j], 0, 0, 0);
    }
    __syncthreads();
  }

#pragma unroll
  for (int j = 0; j < 4; ++j) {
    const int cg = n0 + wn + j * 16 + col;
#pragma unroll
    for (int v = 0; v < 4; ++v)
      C[(size_t)(m0 + wm + quad * 4 + v) * 384 + cg] = (bf16_t)acc[j][v];
  }
}

// ---- out GEMM: C_f32[4096][1024] = A_bf16[4096][lda=384,K=256] @ WcombT_bf16[1024][256]^T ----
// BM=64 BN=128 BK=64, 1D grid 512. XCD-locality: m0=bi%64, n0=bi/64 so the
// 8 col-tiles of a row-slice share an XCD (64%8==0).
__global__ __launch_bounds__(256) void gemm_out(
    const bf16_t* __restrict__ A, const bf16_t* __restrict__ Bt,
    float* __restrict__ C) {
  __shared__ bf16_t As[64][72];
  __shared__ bf16_t Bs[128][72];
  const int tid = threadIdx.x;
  const int wave = tid >> 6, lane = tid & 63;
  const int quad = lane >> 4, col = lane & 15;
  const int wm = (wave >> 1) * 32, wn = (wave & 1) * 64;
  const int bi = blockIdx.x;
  const int m0 = (bi & 63) * 64, n0 = (bi >> 6) * 128;

  f32x4 acc[2][4];
#pragma unroll
  for (int i = 0; i < 2; ++i)
#pragma unroll
    for (int j = 0; j < 4; ++j) acc[i][j] = (f32x4){0.f, 0.f, 0.f, 0.f};

  const int ar = tid >> 2, ac = (tid & 3) * 16;  // A: 64 rows x 64k
  const int br = tid >> 1, bc = (tid & 1) * 32;  // B: 128 rows x 64k
  const bf16_t* aP = A + (size_t)(m0 + ar) * 384 + ac;
  const bf16_t* bP = Bt + (size_t)(n0 + br) * 256 + bc;

  bf16x8 aR0 = *(const bf16x8*)aP, aR1 = *(const bf16x8*)(aP + 8);
  bf16x8 bR0 = *(const bf16x8*)bP, bR1 = *(const bf16x8*)(bP + 8);
  bf16x8 bR2 = *(const bf16x8*)(bP + 16), bR3 = *(const bf16x8*)(bP + 24);

  for (int kt = 0; kt < 4; ++kt) {
    *(bf16x8*)&As[ar][ac] = aR0; *(bf16x8*)&As[ar][ac + 8] = aR1;
    *(bf16x8*)&Bs[br][bc] = bR0; *(bf16x8*)&Bs[br][bc + 8] = bR1;
    *(bf16x8*)&Bs[br][bc + 16] = bR2; *(bf16x8*)&Bs[br][bc + 24] = bR3;
    __syncthreads();
    if (kt < 3) {
      const int k0 = (kt + 1) * 64;
      aR0 = *(const bf16x8*)(aP + k0); aR1 = *(const bf16x8*)(aP + k0 + 8);
      bR0 = *(const bf16x8*)(bP + k0); bR1 = *(const bf16x8*)(bP + k0 + 8);
      bR2 = *(const bf16x8*)(bP + k0 + 16); bR3 = *(const bf16x8*)(bP + k0 + 24);
    }
#pragma unroll
    for (int ks = 0; ks < 2; ++ks) {
      bf16x8 af[2], bfr[4];
#pragma unroll
      for (int i = 0; i < 2; ++i) af[i] = *(const bf16x8*)&As[wm + i * 16 + col][ks * 32 + quad * 8];
#pragma unroll
      for (int j = 0; j < 4; ++j) bfr[j] = *(const bf16x8*)&Bs[wn + j * 16 + col][ks * 32 + quad * 8];
#pragma unroll
      for (int i = 0; i < 2; ++i)
#pragma unroll
        for (int j = 0; j < 4; ++j)
          acc[i][j] = __builtin_amdgcn_mfma_f32_16x16x32_bf16(af[i], bfr[j], acc[i][j], 0, 0, 0);
    }
    __syncthreads();
  }

#pragma unroll
  for (int i = 0; i < 2; ++i) {
    const int rg = m0 + wm + i * 16 + quad * 4;
#pragma unroll
    for (int j = 0; j < 4; ++j) {
      const int cg = n0 + wn + j * 16 + col;
#pragma unroll
      for (int v = 0; v < 4; ++v)
        C[(size_t)(rg + v) * 1024 + cg] = acc[i][j][v];
    }
  }
}

// ---- latent flash attention: balanced blocks, no-max softmax, K/V double
// buffer (1 barrier/tile), Ps same-wave (compiler fence only) ----
// LDS 51KB -> 3 blocks/CU.
__global__ __launch_bounds__(256, 3) void attn_lat(bf16_t* QKV) {
  const int bi = blockIdx.x;
  const int half = bi >> 8, rest = bi & 255;
  const int qt = half ? 127 - (rest >> 1) : (rest >> 1);
  const int hkv = rest & 1, b = half;
  const int tid = threadIdx.x;
  const int wave = tid >> 6, lane = tid & 63;
  const int quad = lane >> 4, col = lane & 15;

  __shared__ bf16_t Ks[2][128][36];
  __shared__ bf16_t Vt[2][32][132];
  __shared__ bf16_t Ps[4][16][132];

  const int qb = qt * 16;
  const size_t rowbase = (size_t)b * 2048;
  const int qcol0 = (hkv * 4 + wave) * 32;

  bf16x8 a_q = *(const bf16x8*)(QKV + (rowbase + qb + col) * 384 + qcol0 + quad * 8);

  f32x4 o0 = (f32x4){0.f, 0.f, 0.f, 0.f};
  f32x4 o1 = (f32x4){0.f, 0.f, 0.f, 0.f};
  float lsum[4] = {0.f, 0.f, 0.f, 0.f};

  const int nkt = (qb >> 7) + 1;
  const float scale = 0.08838834764831843f; // 1/sqrt(128)

  const int kr = tid >> 1, dc = (tid & 1) * 16;
  const bf16_t* kvBase = QKV + (rowbase + kr) * 384 + 256 + hkv * 32 + dc;

  {
    bf16x8 kA = *(const bf16x8*)kvBase, kB = *(const bf16x8*)(kvBase + 8);
    bf16x8 vA = *(const bf16x8*)(kvBase + 64), vB = *(const bf16x8*)(kvBase + 72);
    *(bf16x8*)&Ks[0][kr][dc] = kA;
    *(bf16x8*)&Ks[0][kr][dc + 8] = kB;
#pragma unroll
    for (int t = 0; t < 8; ++t) { Vt[0][dc + t][kr] = vA[t]; Vt[0][dc + 8 + t][kr] = vB[t]; }
  }
  __syncthreads();

  for (int kt = 0; kt < nkt; ++kt) {
    const int cur = kt & 1;
    const int kb = kt * 128;
    const bool more = (kt + 1 < nkt);

    bf16x8 kA, kB, vA, vB;
    if (more) {
      const bf16_t* np = kvBase + (size_t)(kt + 1) * 128 * 384;
      kA = *(const bf16x8*)np; kB = *(const bf16x8*)(np + 8);
      vA = *(const bf16x8*)(np + 64); vB = *(const bf16x8*)(np + 72);
    }

    f32x4 s[8];
#pragma unroll
    for (int k8 = 0; k8 < 8; ++k8) {
      bf16x8 bk = *(const bf16x8*)&Ks[cur][k8 * 16 + col][quad * 8];
      s[k8] = __builtin_amdgcn_mfma_f32_16x16x32_bf16(a_q, bk, (f32x4){0.f, 0.f, 0.f, 0.f}, 0, 0, 0);
    }

    const bool full = (kb + 128 <= qb);
#pragma unroll
    for (int v = 0; v < 4; ++v) {
      const int qr = quad * 4 + v;
      const int qg = qb + qr;
#pragma unroll
      for (int k8 = 0; k8 < 8; ++k8) {
        float xx = s[k8][v] * scale;
        if (!full && (kb + k8 * 16 + col > qg)) xx = -1e30f;
        const float p = __expf(xx);
        lsum[v] += p;
        Ps[wave][qr][k8 * 16 + col] = (bf16_t)p;
      }
    }
    __asm__ __volatile__("" ::: "memory"); // Ps: same-wave LDS, order only

#pragma unroll
    for (int kc = 0; kc < 4; ++kc) {
      bf16x8 a_p = *(const bf16x8*)&Ps[wave][col][kc * 32 + quad * 8];
      bf16x8 bv0 = *(const bf16x8*)&Vt[cur][col][kc * 32 + quad * 8];
      bf16x8 bv1 = *(const bf16x8*)&Vt[cur][16 + col][kc * 32 + quad * 8];
      o0 = __builtin_amdgcn_mfma_f32_16x16x32_bf16(a_p, bv0, o0, 0, 0, 0);
      o1 = __builtin_amdgcn_mfma_f32_16x16x32_bf16(a_p, bv1, o1, 0, 0, 0);
    }

    if (more) {
      *(bf16x8*)&Ks[cur ^ 1][kr][dc] = kA;
      *(bf16x8*)&Ks[cur ^ 1][kr][dc + 8] = kB;
#pragma unroll
      for (int t = 0; t < 8; ++t) { Vt[cur ^ 1][dc + t][kr] = vA[t]; Vt[cur ^ 1][dc + 8 + t][kr] = vB[t]; }
    }
    __syncthreads();
  }

#pragma unroll
  for (int v = 0; v < 4; ++v) {
    float l = lsum[v];
#pragma unroll
    for (int off = 8; off; off >>= 1) l += __shfl_xor(l, off, 64);
    const float inv = 1.f / l;
    const size_t r = (rowbase + qb + quad * 4 + v) * 384 + qcol0;
    QKV[r + col] = (bf16_t)(o0[v] * inv);
    QKV[r + 16 + col] = (bf16_t)(o1[v] * inv);
  }
}

// ---------------------------------------------------------------------------
extern "C" void kernel_launch(void* const* d_in, const int* in_sizes, int n_in,
                              void* d_out, int out_size, void* d_ws, size_t ws_size,
                              hipStream_t stream) {
  (void)in_sizes; (void)n_in; (void)out_size; (void)ws_size;
  const float* x   = (const float*)d_in[0];
  const float* wq  = (const float*)d_in[1];
  const float* wkd = (const float*)d_in[2];
  const float* wvd = (const float*)d_in[3];
  const float* wku = (const float*)d_in[4];
  const float* wvu = (const float*)d_in[5];
  const float* wo  = (const float*)d_in[6];
  float* out = (float*)d_out;

  // Workspace: ~12.8 MB
  bf16_t* WqkvT  = (bf16_t*)d_ws;                 // [384][1024]
  bf16_t* WcombT = WqkvT + (size_t)384 * 1024;    // [1024][256]
  bf16_t* QKV    = WcombT + (size_t)1024 * 256;   // [4096][384]
  bf16_t* Xb     = QKV + (size_t)4096 * 384;      // [4096][1024]

  prep_mfma<<<288, 256, 0, stream>>>(x, wq, wkd, wvd, wku, wvu, wo, Xb, WqkvT, WcombT);
  gemm_qkv<<<384, 256, 0, stream>>>(Xb, WqkvT, QKV);
  attn_lat<<<512, 256, 0, stream>>>(QKV);
  gemm_out<<<512, 256, 0, stream>>>(QKV, WcombT, out);
}

// Round 6
// 136.922 us; speedup vs baseline: 2.5020x; 1.0125x over previous
//
#include <hip/hip_runtime.h>
#include <hip/hip_bf16.h>

// MLA-absorbed latent attention (round 15 = r14 with compile fix).
// r14 failed: __exp2f has no device overload; use __builtin_amdgcn_exp2f
// (lowers to v_exp_f32, D=2^S0 — exactly the folded-scale exp2 path).
// r14 theory stands: (1) x-cast spread 128->384 blocks (grid 544).
// (2) scale*log2e folded into wq_eff at prep; attn uses raw v_exp_f32.

typedef __bf16 bf16_t;
typedef bf16_t bf16x8 __attribute__((ext_vector_type(8)));
typedef float f32x4 __attribute__((ext_vector_type(4)));

__device__ inline bf16x8 cvt8(const float* __restrict__ p) {
  f32x4 a = *(const f32x4*)p, b = *(const f32x4*)(p + 4);
  bf16x8 r;
#pragma unroll
  for (int i = 0; i < 4; ++i) { r[i] = (bf16_t)a[i]; r[4 + i] = (bf16_t)b[i]; }
  return r;
}

// ---- one-shot weight prep, all-MFMA, emits bf16 transposed weights + x cast ----
__global__ __launch_bounds__(256) void prep_mfma(
    const float* __restrict__ x, const float* __restrict__ wq,
    const float* __restrict__ wkd, const float* __restrict__ wvd,
    const float* __restrict__ wku, const float* __restrict__ wvu,
    const float* __restrict__ wo, bf16_t* __restrict__ Xb,
    bf16_t* __restrict__ WqkvT, bf16_t* __restrict__ WcombT) {
  __shared__ __align__(16) char smem[34816];
  const int tid = threadIdx.x;
  const int wave = tid >> 6, lane = tid & 63;
  const int quad = lane >> 4, col = lane & 15;
  const int bi = blockIdx.x;

  if (bi < 64) { // wq_eff^T[32h+l][c] = sum_d wku[l][d]*wq[c][128h+d], pre-scaled
    const float qscale = 0.12751743f; // (1/sqrt(128)) * log2(e), folded for exp2
    const int h = bi >> 3;
    const int c0 = (bi & 7) * 128 + wave * 32;
    f32x4 acc[2][2];
#pragma unroll
    for (int i = 0; i < 2; ++i)
#pragma unroll
      for (int j = 0; j < 2; ++j) acc[i][j] = (f32x4){0.f, 0.f, 0.f, 0.f};
#pragma unroll
    for (int ks = 0; ks < 4; ++ks) {
      const int ko = ks * 32 + quad * 8;
      bf16x8 a0 = cvt8(wku + col * 128 + ko);
      bf16x8 a1 = cvt8(wku + (16 + col) * 128 + ko);
      bf16x8 b0 = cvt8(wq + (size_t)(c0 + col) * 1024 + h * 128 + ko);
      bf16x8 b1 = cvt8(wq + (size_t)(c0 + 16 + col) * 1024 + h * 128 + ko);
      acc[0][0] = __builtin_amdgcn_mfma_f32_16x16x32_bf16(a0, b0, acc[0][0], 0, 0, 0);
      acc[0][1] = __builtin_amdgcn_mfma_f32_16x16x32_bf16(a0, b1, acc[0][1], 0, 0, 0);
      acc[1][0] = __builtin_amdgcn_mfma_f32_16x16x32_bf16(a1, b0, acc[1][0], 0, 0, 0);
      acc[1][1] = __builtin_amdgcn_mfma_f32_16x16x32_bf16(a1, b1, acc[1][1], 0, 0, 0);
    }
#pragma unroll
    for (int ms = 0; ms < 2; ++ms)
#pragma unroll
      for (int ns = 0; ns < 2; ++ns)
#pragma unroll
        for (int v = 0; v < 4; ++v)
          WqkvT[(size_t)(h * 32 + ms * 16 + quad * 4 + v) * 1024 + c0 + ns * 16 + col] =
              (bf16_t)(acc[ms][ns][v] * qscale);
  } else if (bi < 128) { // WcombT[m][32h+l] = sum_d wvu[l][d]*wo[128h+d][m]
    const int b2 = bi - 64;
    const int h = b2 >> 3, m0 = (b2 & 7) * 128;
    bf16_t(*B_lds)[136] = (bf16_t(*)[136])smem; // [m][d]
    {
      const int d = tid >> 1, mh = (tid & 1) * 64;
      const float* wp = wo + (size_t)(h * 128 + d) * 1024 + m0 + mh;
#pragma unroll
      for (int i = 0; i < 16; ++i) {
        f32x4 w4 = *(const f32x4*)(wp + i * 4);
#pragma unroll
        for (int t = 0; t < 4; ++t) B_lds[mh + i * 4 + t][d] = (bf16_t)w4[t];
      }
    }
    __syncthreads();
    f32x4 acc[2][2];
#pragma unroll
    for (int i = 0; i < 2; ++i)
#pragma unroll
      for (int j = 0; j < 2; ++j) acc[i][j] = (f32x4){0.f, 0.f, 0.f, 0.f};
#pragma unroll
    for (int ks = 0; ks < 4; ++ks) {
      const int ko = ks * 32 + quad * 8;
      bf16x8 a0 = cvt8(wvu + col * 128 + ko);
      bf16x8 a1 = cvt8(wvu + (16 + col) * 128 + ko);
      bf16x8 b0 = *(const bf16x8*)&B_lds[wave * 32 + col][ko];
      bf16x8 b1 = *(const bf16x8*)&B_lds[wave * 32 + 16 + col][ko];
      acc[0][0] = __builtin_amdgcn_mfma_f32_16x16x32_bf16(a0, b0, acc[0][0], 0, 0, 0);
      acc[0][1] = __builtin_amdgcn_mfma_f32_16x16x32_bf16(a0, b1, acc[0][1], 0, 0, 0);
      acc[1][0] = __builtin_amdgcn_mfma_f32_16x16x32_bf16(a1, b0, acc[1][0], 0, 0, 0);
      acc[1][1] = __builtin_amdgcn_mfma_f32_16x16x32_bf16(a1, b1, acc[1][1], 0, 0, 0);
    }
#pragma unroll
    for (int ms = 0; ms < 2; ++ms)
#pragma unroll
      for (int ns = 0; ns < 2; ++ns)
#pragma unroll
        for (int v = 0; v < 4; ++v)
          WcombT[(size_t)(m0 + wave * 32 + ns * 16 + col) * 256 +
                 h * 32 + ms * 16 + quad * 4 + v] = (bf16_t)acc[ms][ns][v];
  } else if (bi < 160) { // wk_down/wv_down transpose into WqkvT rows 256..383
    const int b3 = bi - 128;
    const int mat = b3 >> 4, c0 = (b3 & 15) * 64;
    const float* in = mat ? wvd : wkd;
    bf16_t(*tT)[72] = (bf16_t(*)[72])smem;
    {
      const int cc = tid >> 2, jq = (tid & 3) * 16;
      const float* ip = in + (size_t)(c0 + cc) * 64 + jq;
#pragma unroll
      for (int q = 0; q < 4; ++q) {
        f32x4 v4 = *(const f32x4*)(ip + q * 4);
#pragma unroll
        for (int t = 0; t < 4; ++t) tT[jq + q * 4 + t][cc] = (bf16_t)v4[t];
      }
    }
    __syncthreads();
    {
      const int j = tid >> 2, cq = (tid & 3) * 16;
      bf16_t* op = WqkvT + (size_t)(256 + mat * 64 + j) * 1024 + c0 + cq;
      *(bf16x8*)op = *(const bf16x8*)&tT[j][cq];
      *(bf16x8*)(op + 8) = *(const bf16x8*)&tT[j][cq + 8];
    }
  } else { // bi in [160,544): x f32 -> bf16 cast, grid-stride over 2048-elem chunks
    const int cb = bi - 160;
#pragma unroll
    for (int it = 0; it < 6; ++it) {
      const size_t chunk = (size_t)cb + (size_t)it * 384;
      if (chunk < 2048) {
        const size_t off = chunk * 2048 + (size_t)tid * 8;
        *(bf16x8*)(Xb + off) = cvt8(x + off);
      }
    }
  }
}

// ---- QKV GEMM: C_bf16[4096][384] = A_bf16[4096][1024] @ WqkvT_bf16[384][1024]^T ----
// BM=32 BN=128 BK=64, grid (3,128)=384 blocks, wave-tile 16x64.
__global__ __launch_bounds__(256) void gemm_qkv(
    const bf16_t* __restrict__ A, const bf16_t* __restrict__ Bt,
    bf16_t* __restrict__ C) {
  __shared__ bf16_t As[32][72];
  __shared__ bf16_t Bs[128][72];
  const int tid = threadIdx.x;
  const int wave = tid >> 6, lane = tid & 63;
  const int quad = lane >> 4, col = lane & 15;
  const int wm = (wave >> 1) * 16, wn = (wave & 1) * 64;
  const int m0 = blockIdx.y * 32, n0 = blockIdx.x * 128;

  f32x4 acc[4];
#pragma unroll
  for (int j = 0; j < 4; ++j) acc[j] = (f32x4){0.f, 0.f, 0.f, 0.f};

  const int ar = tid >> 3, ac = (tid & 7) * 8;   // A: 32 rows x 64k, 8 bf16/thread
  const int br = tid >> 1, bc = (tid & 1) * 32;  // B: 128 rows x 64k
  const bf16_t* aP = A + (size_t)(m0 + ar) * 1024 + ac;
  const bf16_t* bP = Bt + (size_t)(n0 + br) * 1024 + bc;

  bf16x8 aR0 = *(const bf16x8*)aP;
  bf16x8 bR0 = *(const bf16x8*)bP, bR1 = *(const bf16x8*)(bP + 8);
  bf16x8 bR2 = *(const bf16x8*)(bP + 16), bR3 = *(const bf16x8*)(bP + 24);

  for (int kt = 0; kt < 16; ++kt) {
    *(bf16x8*)&As[ar][ac] = aR0;
    *(bf16x8*)&Bs[br][bc] = bR0; *(bf16x8*)&Bs[br][bc + 8] = bR1;
    *(bf16x8*)&Bs[br][bc + 16] = bR2; *(bf16x8*)&Bs[br][bc + 24] = bR3;
    __syncthreads();
    if (kt < 15) {
      const int k0 = (kt + 1) * 64;
      aR0 = *(const bf16x8*)(aP + k0);
      bR0 = *(const bf16x8*)(bP + k0); bR1 = *(const bf16x8*)(bP + k0 + 8);
      bR2 = *(const bf16x8*)(bP + k0 + 16); bR3 = *(const bf16x8*)(bP + k0 + 24);
    }
#pragma unroll
    for (int ks = 0; ks < 2; ++ks) {
      bf16x8 af = *(const bf16x8*)&As[wm + col][ks * 32 + quad * 8];
      bf16x8 bfr[4];
#pragma unroll
      for (int j = 0; j < 4; ++j) bfr[j] = *(const bf16x8*)&Bs[wn + j * 16 + col][ks * 32 + quad * 8];
#pragma unroll
      for (int j = 0; j < 4; ++j)
        acc[j] = __builtin_amdgcn_mfma_f32_16x16x32_bf16(af, bfr[j], acc[j], 0, 0, 0);
    }
    __syncthreads();
  }

#pragma unroll
  for (int j = 0; j < 4; ++j) {
    const int cg = n0 + wn + j * 16 + col;
#pragma unroll
    for (int v = 0; v < 4; ++v)
      C[(size_t)(m0 + wm + quad * 4 + v) * 384 + cg] = (bf16_t)acc[j][v];
  }
}

// ---- out GEMM: C_f32[4096][1024] = A_bf16[4096][lda=384,K=256] @ WcombT_bf16[1024][256]^T ----
// BM=64 BN=128 BK=64, grid (8,64)=512 blocks, wave-tile 32x64.
__global__ __launch_bounds__(256) void gemm_out(
    const bf16_t* __restrict__ A, const bf16_t* __restrict__ Bt,
    float* __restrict__ C) {
  __shared__ bf16_t As[64][72];
  __shared__ bf16_t Bs[128][72];
  const int tid = threadIdx.x;
  const int wave = tid >> 6, lane = tid & 63;
  const int quad = lane >> 4, col = lane & 15;
  const int wm = (wave >> 1) * 32, wn = (wave & 1) * 64;
  const int m0 = blockIdx.y * 64, n0 = blockIdx.x * 128;

  f32x4 acc[2][4];
#pragma unroll
  for (int i = 0; i < 2; ++i)
#pragma unroll
    for (int j = 0; j < 4; ++j) acc[i][j] = (f32x4){0.f, 0.f, 0.f, 0.f};

  const int ar = tid >> 2, ac = (tid & 3) * 16;  // A: 64 rows x 64k
  const int br = tid >> 1, bc = (tid & 1) * 32;  // B: 128 rows x 64k
  const bf16_t* aP = A + (size_t)(m0 + ar) * 384 + ac;
  const bf16_t* bP = Bt + (size_t)(n0 + br) * 256 + bc;

  bf16x8 aR0 = *(const bf16x8*)aP, aR1 = *(const bf16x8*)(aP + 8);
  bf16x8 bR0 = *(const bf16x8*)bP, bR1 = *(const bf16x8*)(bP + 8);
  bf16x8 bR2 = *(const bf16x8*)(bP + 16), bR3 = *(const bf16x8*)(bP + 24);

  for (int kt = 0; kt < 4; ++kt) {
    *(bf16x8*)&As[ar][ac] = aR0; *(bf16x8*)&As[ar][ac + 8] = aR1;
    *(bf16x8*)&Bs[br][bc] = bR0; *(bf16x8*)&Bs[br][bc + 8] = bR1;
    *(bf16x8*)&Bs[br][bc + 16] = bR2; *(bf16x8*)&Bs[br][bc + 24] = bR3;
    __syncthreads();
    if (kt < 3) {
      const int k0 = (kt + 1) * 64;
      aR0 = *(const bf16x8*)(aP + k0); aR1 = *(const bf16x8*)(aP + k0 + 8);
      bR0 = *(const bf16x8*)(bP + k0); bR1 = *(const bf16x8*)(bP + k0 + 8);
      bR2 = *(const bf16x8*)(bP + k0 + 16); bR3 = *(const bf16x8*)(bP + k0 + 24);
    }
#pragma unroll
    for (int ks = 0; ks < 2; ++ks) {
      bf16x8 af[2], bfr[4];
#pragma unroll
      for (int i = 0; i < 2; ++i) af[i] = *(const bf16x8*)&As[wm + i * 16 + col][ks * 32 + quad * 8];
#pragma unroll
      for (int j = 0; j < 4; ++j) bfr[j] = *(const bf16x8*)&Bs[wn + j * 16 + col][ks * 32 + quad * 8];
#pragma unroll
      for (int i = 0; i < 2; ++i)
#pragma unroll
        for (int j = 0; j < 4; ++j)
          acc[i][j] = __builtin_amdgcn_mfma_f32_16x16x32_bf16(af[i], bfr[j], acc[i][j], 0, 0, 0);
    }
    __syncthreads();
  }

#pragma unroll
  for (int i = 0; i < 2; ++i) {
    const int rg = m0 + wm + i * 16 + quad * 4;
#pragma unroll
    for (int j = 0; j < 4; ++j) {
      const int cg = n0 + wn + j * 16 + col;
#pragma unroll
      for (int v = 0; v < 4; ++v)
        C[(size_t)(rg + v) * 1024 + cg] = acc[i][j][v];
    }
  }
}

// ---- latent flash attention: balanced blocks, no-max softmax (exp2 domain,
// scale pre-folded into Q weights), K/V double buffer, Ps same-wave ----
__global__ __launch_bounds__(256, 3) void attn_lat(bf16_t* QKV) {
  const int bi = blockIdx.x;
  const int half = bi >> 8, rest = bi & 255;
  const int qt = half ? 127 - (rest >> 1) : (rest >> 1);
  const int hkv = rest & 1, b = half;
  const int tid = threadIdx.x;
  const int wave = tid >> 6, lane = tid & 63;
  const int quad = lane >> 4, col = lane & 15;

  __shared__ bf16_t Ks[2][128][36];
  __shared__ bf16_t Vt[2][32][132];
  __shared__ bf16_t Ps[4][16][132];

  const int qb = qt * 16;
  const size_t rowbase = (size_t)b * 2048;
  const int qcol0 = (hkv * 4 + wave) * 32;

  bf16x8 a_q = *(const bf16x8*)(QKV + (rowbase + qb + col) * 384 + qcol0 + quad * 8);

  f32x4 o0 = (f32x4){0.f, 0.f, 0.f, 0.f};
  f32x4 o1 = (f32x4){0.f, 0.f, 0.f, 0.f};
  float lsum[4] = {0.f, 0.f, 0.f, 0.f};

  const int nkt = (qb >> 7) + 1;

  const int kr = tid >> 1, dc = (tid & 1) * 16;
  const bf16_t* kvBase = QKV + (rowbase + kr) * 384 + 256 + hkv * 32 + dc;

  {
    bf16x8 kA = *(const bf16x8*)kvBase, kB = *(const bf16x8*)(kvBase + 8);
    bf16x8 vA = *(const bf16x8*)(kvBase + 64), vB = *(const bf16x8*)(kvBase + 72);
    *(bf16x8*)&Ks[0][kr][dc] = kA;
    *(bf16x8*)&Ks[0][kr][dc + 8] = kB;
#pragma unroll
    for (int t = 0; t < 8; ++t) { Vt[0][dc + t][kr] = vA[t]; Vt[0][dc + 8 + t][kr] = vB[t]; }
  }
  __syncthreads();

  for (int kt = 0; kt < nkt; ++kt) {
    const int cur = kt & 1;
    const int kb = kt * 128;
    const bool more = (kt + 1 < nkt);

    bf16x8 kA, kB, vA, vB;
    if (more) {
      const bf16_t* np = kvBase + (size_t)(kt + 1) * 128 * 384;
      kA = *(const bf16x8*)np; kB = *(const bf16x8*)(np + 8);
      vA = *(const bf16x8*)(np + 64); vB = *(const bf16x8*)(np + 72);
    }

    f32x4 s[8];
#pragma unroll
    for (int k8 = 0; k8 < 8; ++k8) {
      bf16x8 bk = *(const bf16x8*)&Ks[cur][k8 * 16 + col][quad * 8];
      s[k8] = __builtin_amdgcn_mfma_f32_16x16x32_bf16(a_q, bk, (f32x4){0.f, 0.f, 0.f, 0.f}, 0, 0, 0);
    }

    const bool full = (kb + 128 <= qb);
#pragma unroll
    for (int v = 0; v < 4; ++v) {
      const int qr = quad * 4 + v;
      const int qg = qb + qr;
#pragma unroll
      for (int k8 = 0; k8 < 8; ++k8) {
        float xx = s[k8][v]; // scale*log2e pre-folded into Q weights
        if (!full && (kb + k8 * 16 + col > qg)) xx = -1e30f;
        const float p = __builtin_amdgcn_exp2f(xx); // v_exp_f32: D = 2^S0
        lsum[v] += p;
        Ps[wave][qr][k8 * 16 + col] = (bf16_t)p;
      }
    }
    __asm__ __volatile__("" ::: "memory"); // Ps: same-wave LDS, order only

#pragma unroll
    for (int kc = 0; kc < 4; ++kc) {
      bf16x8 a_p = *(const bf16x8*)&Ps[wave][col][kc * 32 + quad * 8];
      bf16x8 bv0 = *(const bf16x8*)&Vt[cur][col][kc * 32 + quad * 8];
      bf16x8 bv1 = *(const bf16x8*)&Vt[cur][16 + col][kc * 32 + quad * 8];
      o0 = __builtin_amdgcn_mfma_f32_16x16x32_bf16(a_p, bv0, o0, 0, 0, 0);
      o1 = __builtin_amdgcn_mfma_f32_16x16x32_bf16(a_p, bv1, o1, 0, 0, 0);
    }

    if (more) {
      *(bf16x8*)&Ks[cur ^ 1][kr][dc] = kA;
      *(bf16x8*)&Ks[cur ^ 1][kr][dc + 8] = kB;
#pragma unroll
      for (int t = 0; t < 8; ++t) { Vt[cur ^ 1][dc + t][kr] = vA[t]; Vt[cur ^ 1][dc + 8 + t][kr] = vB[t]; }
    }
    __syncthreads();
  }

#pragma unroll
  for (int v = 0; v < 4; ++v) {
    float l = lsum[v];
#pragma unroll
    for (int off = 8; off; off >>= 1) l += __shfl_xor(l, off, 64);
    const float inv = 1.f / l;
    const size_t r = (rowbase + qb + quad * 4 + v) * 384 + qcol0;
    QKV[r + col] = (bf16_t)(o0[v] * inv);
    QKV[r + 16 + col] = (bf16_t)(o1[v] * inv);
  }
}

// ---------------------------------------------------------------------------
extern "C" void kernel_launch(void* const* d_in, const int* in_sizes, int n_in,
                              void* d_out, int out_size, void* d_ws, size_t ws_size,
                              hipStream_t stream) {
  (void)in_sizes; (void)n_in; (void)out_size; (void)ws_size;
  const float* x   = (const float*)d_in[0];
  const float* wq  = (const float*)d_in[1];
  const float* wkd = (const float*)d_in[2];
  const float* wvd = (const float*)d_in[3];
  const float* wku = (const float*)d_in[4];
  const float* wvu = (const float*)d_in[5];
  const float* wo  = (const float*)d_in[6];
  float* out = (float*)d_out;

  // Workspace: ~12.8 MB
  bf16_t* WqkvT  = (bf16_t*)d_ws;                 // [384][1024]
  bf16_t* WcombT = WqkvT + (size_t)384 * 1024;    // [1024][256]
  bf16_t* QKV    = WcombT + (size_t)1024 * 256;   // [4096][384]
  bf16_t* Xb     = QKV + (size_t)4096 * 384;      // [4096][1024]

  prep_mfma<<<544, 256, 0, stream>>>(x, wq, wkd, wvd, wku, wvu, wo, Xb, WqkvT, WcombT);
  gemm_qkv<<<dim3(3, 128), 256, 0, stream>>>(Xb, WqkvT, QKV);
  attn_lat<<<512, 256, 0, stream>>>(QKV);
  gemm_out<<<dim3(8, 64), 256, 0, stream>>>(QKV, WcombT, out);
}